// Round 7
// baseline (1129.646 us; speedup 1.0000x reference)
//
#include <hip/hip_runtime.h>

// ---------------------------------------------------------------------------
// RegressionGRU round 16. Layer 1 of the reference is dead code; only layer-0's
// final hidden state feeds the output head.
//
// R15 post-mortem: fusion verified (WRITE_SIZE 109MB in-dispatch; last
// dispatch with idle producers same 245us -> no interference). But per-step
// rose 1.63->1.91us: the split-K re-read of af doubled LDS traffic
// (64->128 ds_read_b128/CU/step) and broke the MFMA stream. Two variables
// bundled again -- same lesson as R14.
//
// R16 (single variable): revert inner loop to R13's proven unified K-loop
// (6 MFMAs per k, one af read per k; gate math after, in exp2 domain).
// Keep R15's fused producer + double-buffered xg unchanged.
// Fallback chain: single-buffer per-chunk xg, then proven R7 kernel.
// ---------------------------------------------------------------------------

typedef __attribute__((ext_vector_type(8))) short short8;
typedef __attribute__((ext_vector_type(4))) float floatx4;

#define T_LEN 512
#define I_DIM 64
#define H_DIM 256
#define NB 16
#define NWG 32
#define L2E 1.4426950408889634f

// ws layout (bytes): wih_bf @ 0 (96K) | h_state @ 128K (512K fp32) | xg @ 1M
#define HSTATE_OFF 131072
#define XG_OFF     1048576
#define XG_PER_T   786432ull          // 32 wgb * 3 planes * 512 slots * 16 B
#define XG_TSTRIDE 393216             // ushorts per t (= XG_PER_T / 2)

__device__ __forceinline__ unsigned short f2bf(float f) {
    union { float f; unsigned u; } v; v.f = f;
    return (unsigned short)((v.u + 0x7FFFu + ((v.u >> 16) & 1u)) >> 16);
}

__device__ __forceinline__ float bf2f(unsigned short u) {
    union { unsigned u; float f; } v; v.u = ((unsigned)u) << 16;
    return v.f;
}

__device__ __forceinline__ short8 pack8v(floatx4 a, floatx4 b) {
    short8 r;
    r[0] = (short)f2bf(a[0]); r[1] = (short)f2bf(a[1]);
    r[2] = (short)f2bf(a[2]); r[3] = (short)f2bf(a[3]);
    r[4] = (short)f2bf(b[0]); r[5] = (short)f2bf(b[1]);
    r[6] = (short)f2bf(b[2]); r[7] = (short)f2bf(b[3]);
    return r;
}

__device__ __forceinline__ short8 pack8s(const float* p, float s) {
    floatx4 a = *(const floatx4*)p;
    floatx4 b = *(const floatx4*)(p + 4);
    short8 r;
    r[0] = (short)f2bf(a[0] * s); r[1] = (short)f2bf(a[1] * s);
    r[2] = (short)f2bf(a[2] * s); r[3] = (short)f2bf(a[3] * s);
    r[4] = (short)f2bf(b[0] * s); r[5] = (short)f2bf(b[1] * s);
    r[6] = (short)f2bf(b[2] * s); r[7] = (short)f2bf(b[3] * s);
    return r;
}

__device__ __forceinline__ float sigm(float a) {
    return 1.0f / (1.0f + __expf(-a));
}

// w_ih fp32 [768x64] -> bf16, blocked: block ((w*6+g)*2+kx)*64+lane, 8/entry.
__global__ void cvt_wih_kernel(const float* __restrict__ w,
                               unsigned short* __restrict__ o) {
    int i = blockIdx.x * 256 + threadIdx.x;
    if (i < 6144) {
        const int l  = i & 63;
        const int kx = (i >> 6) & 1;
        const int g  = (i >> 7) % 6;
        const int wv = (i >> 7) / 6;
        const int row = (g >> 1) * 256 + wv * 32 + (g & 1) * 16 + (l & 15);
        const int col = kx * 32 + (l >> 4) * 8;
        const float* p = w + row * I_DIM + col;
        *(short8*)&o[i * 8] = pack8v(*(const floatx4*)p,
                                     *(const floatx4*)(p + 4));
    }
}

// ---------------------------------------------------------------------------
// xg production body (per wave): 4 consecutive local t's for one wgb.
// Values carry fused biases and sigmoid/tanh log2 scales:
//   gate r,z: (x.Wih + b_ih + b_hh) * log2(e)
//   gate n  : (x.Wih + b_ih) * 2*log2(e)
// Verified lane mapping: producer C-frag lane (m16,quad) == consumer (m16,quad).
// ---------------------------------------------------------------------------
__device__ __forceinline__ void xg_produce_wave(
    const float* __restrict__ x,
    const unsigned short* __restrict__ wih_bf,
    unsigned short* __restrict__ xg,
    const float* __restrict__ b_ih,
    const float* __restrict__ b_hh,
    int t0, int tl0, int wgb, int lane)
{
    const int m16  = lane & 15;
    const int quad = lane >> 4;

    short8 af0[4], af1[4];
    #pragma unroll
    for (int j = 0; j < 4; ++j) {
        const float* xp = x + ((long)(wgb * 16 + m16) * T_LEN + (t0 + tl0 + j))
                              * I_DIM + quad * 8;
        af0[j] = pack8v(*(const floatx4*)xp,        *(const floatx4*)(xp + 4));
        af1[j] = pack8v(*(const floatx4*)(xp + 32), *(const floatx4*)(xp + 36));
    }

    #pragma unroll 1
    for (int wp = 0; wp < 8; ++wp) {
        #pragma unroll 1
        for (int gate = 0; gate < 3; ++gate) {
            const int u0 = wp * 32 + m16;
            float bs0, bs1, sc;
            if (gate < 2) {
                bs0 = b_ih[gate * 256 + u0]      + b_hh[gate * 256 + u0];
                bs1 = b_ih[gate * 256 + u0 + 16] + b_hh[gate * 256 + u0 + 16];
                sc  = L2E;
            } else {
                bs0 = b_ih[512 + u0];
                bs1 = b_ih[512 + u0 + 16];
                sc  = 2.0f * L2E;
            }
            const int gb = (wp * 6 + gate * 2) * 2;
            short8 b00 = *(const short8*)&wih_bf[((gb + 0) * 64 + lane) * 8];
            short8 b01 = *(const short8*)&wih_bf[((gb + 1) * 64 + lane) * 8];
            short8 b10 = *(const short8*)&wih_bf[((gb + 2) * 64 + lane) * 8];
            short8 b11 = *(const short8*)&wih_bf[((gb + 3) * 64 + lane) * 8];
            #pragma unroll
            for (int j = 0; j < 4; ++j) {
                floatx4 a0 = {0, 0, 0, 0}, a1 = {0, 0, 0, 0};
                a0 = __builtin_amdgcn_mfma_f32_16x16x32_bf16(af0[j], b00, a0, 0, 0, 0);
                a0 = __builtin_amdgcn_mfma_f32_16x16x32_bf16(af1[j], b01, a0, 0, 0, 0);
                a1 = __builtin_amdgcn_mfma_f32_16x16x32_bf16(af0[j], b10, a1, 0, 0, 0);
                a1 = __builtin_amdgcn_mfma_f32_16x16x32_bf16(af1[j], b11, a1, 0, 0, 0);
                short8 pk;
                pk[0] = (short)f2bf((a0[0] + bs0) * sc);
                pk[1] = (short)f2bf((a0[1] + bs0) * sc);
                pk[2] = (short)f2bf((a0[2] + bs0) * sc);
                pk[3] = (short)f2bf((a0[3] + bs0) * sc);
                pk[4] = (short)f2bf((a1[0] + bs1) * sc);
                pk[5] = (short)f2bf((a1[1] + bs1) * sc);
                pk[6] = (short)f2bf((a1[2] + bs1) * sc);
                pk[7] = (short)f2bf((a1[3] + bs1) * sc);
                long off = ((((long)(tl0 + j) * 32 + wgb) * 3 + gate) * 512
                            + wp * 64 + lane) * 8;
                *(short8*)&xg[off] = pk;
            }
        }
    }
}

// standalone producer for chunk 0 (and single-buffer mode)
__global__ __launch_bounds__(256) void xg_kernel(
    const float* __restrict__ x,
    const unsigned short* __restrict__ wih_bf,
    unsigned short* __restrict__ xg,
    const float* __restrict__ b_ih,
    const float* __restrict__ b_hh,
    int t0)
{
    const int tid  = threadIdx.x;
    const int wv   = tid >> 6;
    const int lane = tid & 63;
    const int wgb  = blockIdx.x & 31;
    const int tl0  = (blockIdx.x >> 5) * 16 + wv * 4;
    xg_produce_wave(x, wih_bf, xg, b_ih, b_hh, t0, tl0, wgb, lane);
}

// ---------------------------------------------------------------------------
// Fused scan + next-chunk producer.
// WGs [0,32): recurrence scan over [t0, t0+tlen) reading xg_cur.
// WGs [32,grid): produce xg for [t0+tlen, t0+2*tlen) into xg_next (if any).
// Scan: 8 waves, all whh in registers, LDS = 16KB h dbuf, raw lgkm barrier.
// R16: unified K-loop restored (6 MFMAs per k, single af read) -- R13's
// proven 1.63us/step inner loop.
// ---------------------------------------------------------------------------
__global__ __launch_bounds__(512, 2) void gru_scan8(
    const unsigned short* __restrict__ xg,
    unsigned short* __restrict__ xg_next,      // may be null
    const float* __restrict__ x,
    const unsigned short* __restrict__ wih_bf,
    const float* __restrict__ b_ih,
    const float* __restrict__ b_hh,
    const float* __restrict__ w_hh,
    const float* __restrict__ w_lin,
    const float* __restrict__ b_lin,
    float* __restrict__ h_state,        // [512][256] fp32 chunk carry
    float* __restrict__ out,            // [1024]
    int t0, int tlen, int last)
{
    __shared__ __align__(16) unsigned short hbf[1024 * 8];     // 16 KB dbuf

    const int tid  = threadIdx.x;
    const int wave = tid >> 6;
    const int lane = tid & 63;
    const int m16  = lane & 15;
    const int quad = lane >> 4;
    const int wg   = blockIdx.x;

    // ---- producer WGs: next chunk's xg on the otherwise-idle CUs ---------
    if (wg >= NWG) {
        const int t0n = t0 + tlen;
        if (xg_next != nullptr && t0n < T_LEN) {
            const int nwaves = (gridDim.x - NWG) * 8;
            const int ntask  = 32 * (tlen >> 2);       // wgb x 4-t groups
            for (int task = (wg - NWG) * 8 + wave; task < ntask; task += nwaves)
                xg_produce_wave(x, wih_bf, xg_next, b_ih, b_hh,
                                t0n, (task >> 5) * 4, task & 31, lane);
        }
        return;
    }

    for (int b = tid; b < 1024; b += 512)
        *(short8*)&hbf[b * 8] = (short8)0;

    // ---- h carry-in: zeros at t0==0, else h_state ------------------------
    float h_old[8] = {0, 0, 0, 0, 0, 0, 0, 0};
    if (t0 > 0) {
        unsigned short* hbn = &hbf[(t0 & 1) * 512 * 8];
        #pragma unroll
        for (int i = 0; i < 2; ++i) {
            #pragma unroll
            for (int r = 0; r < 4; ++r) {
                float v = h_state[(long)(wg * NB + quad * 4 + r) * H_DIM
                                  + wave * 32 + i * 16 + m16];
                h_old[i * 4 + r] = v;
                hbn[(wave * 64 + (i * 2 + (m16 >> 3)) * 16 + quad * 4 + r) * 8
                    + (m16 & 7)] = f2bf(v);
            }
        }
    }

    // ---- ALL whh gate weights -> registers, pre-scaled -------------------
    short8 whh[3][2][8];
    #pragma unroll
    for (int g = 0; g < 3; ++g) {
        const float sc = (g < 2) ? L2E : 2.0f * L2E;
        #pragma unroll
        for (int i = 0; i < 2; ++i) {
            const float* rp = w_hh
                + (long)(g * 256 + wave * 32 + i * 16 + m16) * H_DIM;
            #pragma unroll
            for (int k = 0; k < 8; ++k)
                whh[g][i][k] = pack8s(rp + k * 32 + quad * 8, sc);
        }
    }
    float anb[2];   // 2*log2(e) * b_hh_n, folded into aN init
    anb[0] = 2.0f * L2E * b_hh[512 + wave * 32 + m16];
    anb[1] = 2.0f * L2E * b_hh[512 + wave * 32 + 16 + m16];

    // xg addressing (ushorts): slot = tid per plane; planes 4096 apart.
    const unsigned short* xgb = xg + (long)wg * 12288 + tid * 8;
    short8 pf0 = *(const short8*)&xgb[0];
    short8 pf1 = *(const short8*)&xgb[4096];
    short8 xnc = *(const short8*)&xgb[8192];
    const unsigned short* xgn = xgb + XG_TSTRIDE;   // -> step 1 (tlen >= 2)

    __syncthreads();

    #pragma unroll 1
    for (int tt = 0; tt < tlen; ++tt) {
        const int t = t0 + tt;
        // ---- acc init from prefetched xg (biases already folded) ---------
        floatx4 aR[2], aZ[2], aN[2];
        #pragma unroll
        for (int i = 0; i < 2; ++i) {
            #pragma unroll
            for (int r = 0; r < 4; ++r) {
                aR[i][r] = bf2f((unsigned short)pf0[i * 4 + r]);
                aZ[i][r] = bf2f((unsigned short)pf1[i * 4 + r]);
            }
            aN[i] = (floatx4){anb[i], anb[i], anb[i], anb[i]};
        }
        // ---- prefetch r,z planes of t+1 (full step of slack to use) ------
        pf0 = *(const short8*)&xgn[0];
        pf1 = *(const short8*)&xgn[4096];

        // ---- hg: h @ w_hh^T, unified K-loop, all weights in registers ----
        const unsigned short* hb = &hbf[(t & 1) * 512 * 8];
        #pragma unroll
        for (int k = 0; k < 8; ++k) {
            short8 af = *(const short8*)&hb[(k * 64 + lane) * 8];
            aR[0] = __builtin_amdgcn_mfma_f32_16x16x32_bf16(af, whh[0][0][k], aR[0], 0, 0, 0);
            aR[1] = __builtin_amdgcn_mfma_f32_16x16x32_bf16(af, whh[0][1][k], aR[1], 0, 0, 0);
            aZ[0] = __builtin_amdgcn_mfma_f32_16x16x32_bf16(af, whh[1][0][k], aZ[0], 0, 0, 0);
            aZ[1] = __builtin_amdgcn_mfma_f32_16x16x32_bf16(af, whh[1][1][k], aZ[1], 0, 0, 0);
            aN[0] = __builtin_amdgcn_mfma_f32_16x16x32_bf16(af, whh[2][0][k], aN[0], 0, 0, 0);
            aN[1] = __builtin_amdgcn_mfma_f32_16x16x32_bf16(af, whh[2][1][k], aN[1], 0, 0, 0);
        }

        // ---- gates (exp2 domain, lane-local) + h update ------------------
        unsigned short* hbn = &hbf[((t + 1) & 1) * 512 * 8];
        #pragma unroll
        for (int i = 0; i < 2; ++i) {
            float hv0, hv1, hv2, hv3;
            #pragma unroll
            for (int r = 0; r < 4; ++r) {
                const int e = i * 4 + r;
                float xnv = bf2f((unsigned short)xnc[i * 4 + r]);
                float rr = __builtin_amdgcn_rcpf(1.0f + __builtin_amdgcn_exp2f(-aR[i][r]));
                float zz = __builtin_amdgcn_rcpf(1.0f + __builtin_amdgcn_exp2f(-aZ[i][r]));
                float av = xnv + rr * aN[i][r];               // = 2*log2e*av
                float tn = 1.0f - 2.0f * __builtin_amdgcn_rcpf(1.0f + __builtin_amdgcn_exp2f(av));
                float hv = tn + zz * (h_old[e] - tn);         // (1-z)n + z*h
                h_old[e] = hv;
                if (r == 0) hv0 = hv; else if (r == 1) hv1 = hv;
                else if (r == 2) hv2 = hv; else hv3 = hv;
            }
            unsigned pk0, pk1;
            asm("v_cvt_pk_bf16_f32 %0, %1, %2" : "=v"(pk0) : "v"(hv0), "v"(hv1));
            asm("v_cvt_pk_bf16_f32 %0, %1, %2" : "=v"(pk1) : "v"(hv2), "v"(hv3));
            unsigned short* wb = &hbn[(wave * 64 + (i * 2 + (m16 >> 3)) * 16
                                       + quad * 4) * 8 + (m16 & 7)];
            wb[0]  = (unsigned short)(pk0 & 0xffffu);
            wb[8]  = (unsigned short)(pk0 >> 16);
            wb[16] = (unsigned short)(pk1 & 0xffffu);
            wb[24] = (unsigned short)(pk1 >> 16);
        }

        // ---- n-plane of t+1: loaded late (slack = barrier+MFMA ~1500cy) --
        xnc = *(const short8*)&xgn[8192];
        if (tt < tlen - 2) xgn += XG_TSTRIDE;

        // ---- RAW barrier: drain LDS only; xg loads stay in flight --------
        asm volatile("s_waitcnt lgkmcnt(0)" ::: "memory");
        __builtin_amdgcn_s_barrier();
    }

    // ---- h carry-out ------------------------------------------------------
    #pragma unroll
    for (int i = 0; i < 2; ++i)
        #pragma unroll
        for (int r = 0; r < 4; ++r)
            h_state[(long)(wg * NB + quad * 4 + r) * H_DIM
                    + wave * 32 + i * 16 + m16] = h_old[i * 4 + r];

    if (!last) return;

    // ---- epilogue: p = sigmoid(h_last . w_lin + b) -----------------------
    __syncthreads();
    float* hfin = (float*)hbf;
    #pragma unroll
    for (int i = 0; i < 2; ++i)
        #pragma unroll
        for (int r = 0; r < 4; ++r)
            hfin[(quad * 4 + r) * 256 + wave * 32 + i * 16 + m16] =
                h_old[i * 4 + r];
    __syncthreads();

    const int m = tid >> 5, j = tid & 31;
    float s = 0.0f;
    #pragma unroll
    for (int c = 0; c < 8; ++c)
        s += hfin[m * 256 + j + c * 32] * w_lin[j + c * 32];
    #pragma unroll
    for (int d = 16; d > 0; d >>= 1) s += __shfl_down(s, d, 32);
    if (j == 0) {
        float p = sigm(s + b_lin[0]);
        const int b = wg * NB + m;
        out[2 * b]     = p;
        out[2 * b + 1] = 1.0f - p;
    }
}

// ---------------------------------------------------------------------------
// Fallback: proven R7 kernel (1786 us) if workspace can't hold a 32-step chunk.
// ---------------------------------------------------------------------------
__global__ __launch_bounds__(512, 1) void gru_kernel(
    const float* __restrict__ x,
    const float* __restrict__ w_hh,
    const float* __restrict__ b_ih,
    const float* __restrict__ b_hh,
    const unsigned short* __restrict__ wih_ws,
    const float* __restrict__ w_lin,
    const float* __restrict__ b_lin,
    float* __restrict__ out)
{
    __shared__ __align__(16) unsigned short whn_lds[8192 * 8];
    __shared__ __align__(16) unsigned short hbf[1024 * 8];
    __shared__ __align__(16) unsigned short bias_lds[512 * 8];

    const int tid  = threadIdx.x;
    const int wave = tid >> 6;
    const int lane = tid & 63;
    const int m16  = lane & 15;
    const int quad = lane >> 4;
    const int wg   = blockIdx.x;

    for (int b = tid; b < 8192; b += 512) {
        const int l = b & 63;
        const int k = (b >> 6) & 7;
        const int g = (b >> 9) & 1;
        const int w = b >> 10;
        const int row = 512 + w * 32 + g * 16 + (l & 15);
        const int col = k * 32 + (l >> 4) * 8;
        const float* p = w_hh + row * H_DIM + col;
        *(short8*)&whn_lds[b * 8] = pack8v(*(const floatx4*)p,
                                           *(const floatx4*)(p + 4));
    }
    for (int b = tid; b < 1024; b += 512)
        *(short8*)&hbf[b * 8] = (short8)0;

    {
        const int u0 = wave * 32 + m16, u1 = u0 + 16;
        unsigned short* bl = &bias_lds[tid * 8];
        bl[0] = f2bf(b_ih[u0] + b_hh[u0]);
        bl[1] = f2bf(b_ih[u1] + b_hh[u1]);
        bl[2] = f2bf(b_ih[256 + u0] + b_hh[256 + u0]);
        bl[3] = f2bf(b_ih[256 + u1] + b_hh[256 + u1]);
        bl[4] = f2bf(b_hh[512 + u0]);
        bl[5] = f2bf(b_hh[512 + u1]);
        bl[6] = f2bf(b_ih[512 + u0]);
        bl[7] = f2bf(b_ih[512 + u1]);
    }

    short8 whh[4][8];
    #pragma unroll
    for (int g = 0; g < 4; ++g) {
        const int row = (g >> 1) * 256 + wave * 32 + (g & 1) * 16 + m16;
        const float* rp = w_hh + row * H_DIM;
        #pragma unroll
        for (int k = 0; k < 8; ++k) {
            const float* p = rp + k * 32 + quad * 8;
            whh[g][k] = pack8v(*(const floatx4*)p, *(const floatx4*)(p + 4));
        }
    }

    short8 wi[12];
    {
        const unsigned short* wib = &wih_ws[(wave * 6 * 2 * 64 + lane) * 8];
        #pragma unroll
        for (int j = 0; j < 12; ++j)
            wi[j] = *(const short8*)&wib[j * 64 * 8];
    }

    float h_old[8] = {0, 0, 0, 0, 0, 0, 0, 0};
    const float* xbase = x + (long)(wg * NB + m16) * T_LEN * I_DIM + quad * 8;

    __syncthreads();

    #pragma unroll 1
    for (int t = 0; t < T_LEN; ++t) {
        const float* xt = xbase + t * I_DIM;
        floatx4 x0 = *(const floatx4*)(xt);
        floatx4 x1 = *(const floatx4*)(xt + 4);
        floatx4 x2 = *(const floatx4*)(xt + 32);
        floatx4 x3 = *(const floatx4*)(xt + 36);

        floatx4 acc[4], an[2], xnl[2];
        #pragma unroll
        for (int g = 0; g < 4; ++g) acc[g] = (floatx4){0, 0, 0, 0};
        an[0] = an[1] = xnl[0] = xnl[1] = (floatx4){0, 0, 0, 0};

        const unsigned short* hb  = &hbf[(t & 1) * 512 * 8];
        const unsigned short* wnb = &whn_lds[(wave * 2 * 8 * 64 + lane) * 8];
        #pragma unroll
        for (int k = 0; k < 8; ++k) {
            short8 af  = *(const short8*)&hb[(k * 64 + lane) * 8];
            short8 wn0 = *(const short8*)&wnb[(k * 64) * 8];
            short8 wn1 = *(const short8*)&wnb[((8 + k) * 64) * 8];
            acc[0] = __builtin_amdgcn_mfma_f32_16x16x32_bf16(af, whh[0][k], acc[0], 0, 0, 0);
            acc[1] = __builtin_amdgcn_mfma_f32_16x16x32_bf16(af, whh[1][k], acc[1], 0, 0, 0);
            acc[2] = __builtin_amdgcn_mfma_f32_16x16x32_bf16(af, whh[2][k], acc[2], 0, 0, 0);
            acc[3] = __builtin_amdgcn_mfma_f32_16x16x32_bf16(af, whh[3][k], acc[3], 0, 0, 0);
            an[0]  = __builtin_amdgcn_mfma_f32_16x16x32_bf16(af, wn0, an[0], 0, 0, 0);
            an[1]  = __builtin_amdgcn_mfma_f32_16x16x32_bf16(af, wn1, an[1], 0, 0, 0);
        }

        short8 xa = pack8v(x0, x1);
        acc[0] = __builtin_amdgcn_mfma_f32_16x16x32_bf16(xa, wi[0],  acc[0], 0, 0, 0);
        acc[1] = __builtin_amdgcn_mfma_f32_16x16x32_bf16(xa, wi[2],  acc[1], 0, 0, 0);
        acc[2] = __builtin_amdgcn_mfma_f32_16x16x32_bf16(xa, wi[4],  acc[2], 0, 0, 0);
        acc[3] = __builtin_amdgcn_mfma_f32_16x16x32_bf16(xa, wi[6],  acc[3], 0, 0, 0);
        xnl[0] = __builtin_amdgcn_mfma_f32_16x16x32_bf16(xa, wi[8],  xnl[0], 0, 0, 0);
        xnl[1] = __builtin_amdgcn_mfma_f32_16x16x32_bf16(xa, wi[10], xnl[1], 0, 0, 0);
        xa = pack8v(x2, x3);
        acc[0] = __builtin_amdgcn_mfma_f32_16x16x32_bf16(xa, wi[1],  acc[0], 0, 0, 0);
        acc[1] = __builtin_amdgcn_mfma_f32_16x16x32_bf16(xa, wi[3],  acc[1], 0, 0, 0);
        acc[2] = __builtin_amdgcn_mfma_f32_16x16x32_bf16(xa, wi[5],  acc[2], 0, 0, 0);
        acc[3] = __builtin_amdgcn_mfma_f32_16x16x32_bf16(xa, wi[7],  acc[3], 0, 0, 0);
        xnl[0] = __builtin_amdgcn_mfma_f32_16x16x32_bf16(xa, wi[9],  xnl[0], 0, 0, 0);
        xnl[1] = __builtin_amdgcn_mfma_f32_16x16x32_bf16(xa, wi[11], xnl[1], 0, 0, 0);

        short8 bv = *(const short8*)&bias_lds[tid * 8];
        unsigned short* hbn = &hbf[((t + 1) & 1) * 512 * 8];
        #pragma unroll
        for (int i = 0; i < 2; ++i) {
            #pragma unroll
            for (int r = 0; r < 4; ++r) {
                const int idx = i * 4 + r;
                float rr = sigm(acc[i][r]     + bf2f((unsigned short)bv[i]));
                float zz = sigm(acc[2 + i][r] + bf2f((unsigned short)bv[2 + i]));
                float av = xnl[i][r] + bf2f((unsigned short)bv[6 + i])
                         + rr * (an[i][r] + bf2f((unsigned short)bv[4 + i]));
                float nn = 1.0f - 2.0f / (1.0f + __expf(2.0f * av));
                float hn = (1.0f - zz) * nn + zz * h_old[idx];
                h_old[idx] = hn;
                hbn[(wave * 64 + (i * 2 + (m16 >> 3)) * 16 + quad * 4 + r) * 8
                    + (m16 & 7)] = f2bf(hn);
            }
        }
        __syncthreads();
    }

    __syncthreads();
    float* hfin = (float*)hbf;
    #pragma unroll
    for (int i = 0; i < 2; ++i)
        #pragma unroll
        for (int r = 0; r < 4; ++r)
            hfin[(quad * 4 + r) * 256 + wave * 32 + i * 16 + m16] =
                h_old[i * 4 + r];
    __syncthreads();

    const int m = tid >> 5, j = tid & 31;
    float s = 0.0f;
    #pragma unroll
    for (int c = 0; c < 8; ++c)
        s += hfin[m * 256 + j + c * 32] * w_lin[j + c * 32];
    #pragma unroll
    for (int d = 16; d > 0; d >>= 1) s += __shfl_down(s, d, 32);
    if (j == 0) {
        float p = sigm(s + b_lin[0]);
        const int b = wg * NB + m;
        out[2 * b]     = p;
        out[2 * b + 1] = 1.0f - p;
    }
}

extern "C" void kernel_launch(void* const* d_in, const int* in_sizes, int n_in,
                              void* d_out, int out_size, void* d_ws, size_t ws_size,
                              hipStream_t stream) {
    const float* x     = (const float*)d_in[0];
    const float* w_ih0 = (const float*)d_in[1];
    const float* w_hh0 = (const float*)d_in[2];
    const float* b_ih0 = (const float*)d_in[3];
    const float* b_hh0 = (const float*)d_in[4];
    // d_in[5..8]: layer-1 params — dead code in the reference
    const float* w_lin = (const float*)d_in[9];
    const float* b_lin = (const float*)d_in[10];
    float* out = (float*)d_out;

    unsigned short* wih_bf = (unsigned short*)d_ws;
    cvt_wih_kernel<<<24, 256, 0, stream>>>(w_ih0, wih_bf);

    float* h_state = (float*)((char*)d_ws + HSTATE_OFF);

    // double-buffer chunk length (fused producer path)
    int Tc2 = 0;
    for (int c = 256; c >= 32; c >>= 1)
        if (ws_size >= XG_OFF + 2ull * c * XG_PER_T) { Tc2 = c; break; }

    if (Tc2) {
        unsigned short* xgA = (unsigned short*)((char*)d_ws + XG_OFF);
        unsigned short* xgB = xgA + (size_t)Tc2 * (XG_PER_T / 2);
        xg_kernel<<<32 * (Tc2 / 16), 256, 0, stream>>>(x, wih_bf, xgA,
                                                       b_ih0, b_hh0, 0);
        int par = 0;
        for (int t0 = 0; t0 < T_LEN; t0 += Tc2) {
            unsigned short* cur = par ? xgB : xgA;
            unsigned short* nxt = par ? xgA : xgB;
            gru_scan8<<<256, 512, 0, stream>>>(cur, nxt, x, wih_bf,
                                               b_ih0, b_hh0, w_hh0,
                                               w_lin, b_lin, h_state, out,
                                               t0, Tc2,
                                               (t0 + Tc2 >= T_LEN) ? 1 : 0);
            par ^= 1;
        }
        return;
    }

    // single-buffer path: per-chunk standalone xg + 32-WG scan
    int Tc = 0;
    for (int c = 256; c >= 32; c >>= 1)
        if (ws_size >= XG_OFF + (size_t)c * XG_PER_T) { Tc = c; break; }

    if (Tc) {
        unsigned short* xg = (unsigned short*)((char*)d_ws + XG_OFF);
        for (int t0 = 0; t0 < T_LEN; t0 += Tc) {
            xg_kernel<<<32 * (Tc / 16), 256, 0, stream>>>(x, wih_bf, xg,
                                                          b_ih0, b_hh0, t0);
            gru_scan8<<<NWG, 512, 0, stream>>>(xg, nullptr, x, wih_bf,
                                               b_ih0, b_hh0, w_hh0,
                                               w_lin, b_lin, h_state, out,
                                               t0, Tc,
                                               (t0 + Tc >= T_LEN) ? 1 : 0);
        }
    } else {
        gru_kernel<<<NWG, 512, 0, stream>>>(x, w_hh0, b_ih0, b_hh0, wih_bf,
                                            w_lin, b_lin, out);
    }
}

// Round 8
// 859.185 us; speedup vs baseline: 1.3148x; 1.3148x over previous
//
#include <hip/hip_runtime.h>

// ---------------------------------------------------------------------------
// RegressionGRU round 17. Layer 1 of the reference is dead code; only layer-0's
// final hidden state feeds the output head.
//
// R15 vs R16 was an accidental clean A/B (same launch structure, one loop
// variable): split-K + in-place sigmoids = 245us/128st vs unified = 275us.
// Split-K is ~560cy/step FASTER; the earlier "split-K regressed" read was
// contaminated by prologue amortization. Two-point fit (R13: 413=P+256s,
// R16: 275=P+128s) gives s=1.08us/step, P~137us/chunk -- the per-chunk
// PROLOGUE is first-order. Fusion itself was a net wash (R13 unfused = 962
// best); drop it.
//
// R17: (1) unfused R13 launch (Tc=256, grid 32, standalone xg);
// (2) R15's A/B-proven split-K inner loop; (3) NEW: w_hh pre-packed to
// pre-scaled bf16 in ws (cvt_whh_kernel) -> scan prologue = 48 coalesced
// 16B loads/thread, zero pack VALU. Fallback: proven R7 kernel.
// ---------------------------------------------------------------------------

typedef __attribute__((ext_vector_type(8))) short short8;
typedef __attribute__((ext_vector_type(4))) float floatx4;

#define T_LEN 512
#define I_DIM 64
#define H_DIM 256
#define NB 16
#define NWG 32
#define L2E 1.4426950408889634f

// ws layout (bytes):
//   wih_bf  @ 0        (96 KB)
//   h_state @ 131072   (512 KB fp32)
//   whh_bf  @ 655360   (384 KB, pre-scaled bf16, ends exactly at XG_OFF)
//   xg      @ 1048576
#define HSTATE_OFF 131072
#define WHH_OFF    655360
#define XG_OFF     1048576
#define XG_PER_T   786432ull          // 32 wgb * 3 planes * 512 slots * 16 B
#define XG_TSTRIDE 393216             // ushorts per t (= XG_PER_T / 2)

__device__ __forceinline__ unsigned short f2bf(float f) {
    union { float f; unsigned u; } v; v.f = f;
    return (unsigned short)((v.u + 0x7FFFu + ((v.u >> 16) & 1u)) >> 16);
}

__device__ __forceinline__ float bf2f(unsigned short u) {
    union { unsigned u; float f; } v; v.u = ((unsigned)u) << 16;
    return v.f;
}

__device__ __forceinline__ short8 pack8v(floatx4 a, floatx4 b) {
    short8 r;
    r[0] = (short)f2bf(a[0]); r[1] = (short)f2bf(a[1]);
    r[2] = (short)f2bf(a[2]); r[3] = (short)f2bf(a[3]);
    r[4] = (short)f2bf(b[0]); r[5] = (short)f2bf(b[1]);
    r[6] = (short)f2bf(b[2]); r[7] = (short)f2bf(b[3]);
    return r;
}

__device__ __forceinline__ short8 pack8s(const float* p, float s) {
    floatx4 a = *(const floatx4*)p;
    floatx4 b = *(const floatx4*)(p + 4);
    short8 r;
    r[0] = (short)f2bf(a[0] * s); r[1] = (short)f2bf(a[1] * s);
    r[2] = (short)f2bf(a[2] * s); r[3] = (short)f2bf(a[3] * s);
    r[4] = (short)f2bf(b[0] * s); r[5] = (short)f2bf(b[1] * s);
    r[6] = (short)f2bf(b[2] * s); r[7] = (short)f2bf(b[3] * s);
    return r;
}

__device__ __forceinline__ float sigm(float a) {
    return 1.0f / (1.0f + __expf(-a));
}

// w_ih fp32 [768x64] -> bf16, blocked: block ((w*6+g)*2+kx)*64+lane, 8/entry.
__global__ void cvt_wih_kernel(const float* __restrict__ w,
                               unsigned short* __restrict__ o) {
    int i = blockIdx.x * 256 + threadIdx.x;
    if (i < 6144) {
        const int l  = i & 63;
        const int kx = (i >> 6) & 1;
        const int g  = (i >> 7) % 6;
        const int wv = (i >> 7) / 6;
        const int row = (g >> 1) * 256 + wv * 32 + (g & 1) * 16 + (l & 15);
        const int col = kx * 32 + (l >> 4) * 8;
        const float* p = w + row * I_DIM + col;
        *(short8*)&o[i * 8] = pack8v(*(const floatx4*)p,
                                     *(const floatx4*)(p + 4));
    }
}

// w_hh fp32 [768x256] -> pre-scaled bf16 in the exact fragment layout the
// scan consumes: block b = ((wv*3+g)*2+ii)*8+k, entry (b*64+lane)*8.
// r,z rows scaled by log2(e); n rows by 2*log2(e).
__global__ void cvt_whh_kernel(const float* __restrict__ w,
                               unsigned short* __restrict__ o) {
    int i = blockIdx.x * 256 + threadIdx.x;      // 96 blocks -> 24576 entries
    if (i < 24576) {
        const int lane = i & 63;
        const int k  = (i >> 6) & 7;
        const int ii = (i >> 9) & 1;
        const int g  = (i >> 10) % 3;
        const int wv = (i >> 10) / 3;
        const int row = g * 256 + wv * 32 + ii * 16 + (lane & 15);
        const int col = k * 32 + (lane >> 4) * 8;
        const float sc = (g < 2) ? L2E : 2.0f * L2E;
        *(short8*)&o[i * 8] = pack8s(w + (long)row * H_DIM + col, sc);
    }
}

// ---------------------------------------------------------------------------
// xg producer: xg[(t*32+wgb)*3+gate][slot] holds 8 bf16 per 16B slot; values
// carry the fused biases and sigmoid/tanh log2 scales:
//   gate r,z: (x.Wih + b_ih + b_hh) * log2(e)
//   gate n  : (x.Wih + b_ih) * 2*log2(e)
// Verified lane mapping: producer C-frag lane (m16,quad) == consumer (m16,quad).
// ---------------------------------------------------------------------------
__global__ __launch_bounds__(256) void xg_kernel(
    const float* __restrict__ x,
    const unsigned short* __restrict__ wih_bf,
    unsigned short* __restrict__ xg,
    const float* __restrict__ b_ih,
    const float* __restrict__ b_hh,
    int t0)
{
    const int tid  = threadIdx.x;
    const int wv   = tid >> 6;
    const int lane = tid & 63;
    const int m16  = lane & 15;
    const int quad = lane >> 4;
    const int wgb  = blockIdx.x & 31;
    const int tl0  = (blockIdx.x >> 5) * 16 + wv * 4;   // local t base

    short8 af0[4], af1[4];
    #pragma unroll
    for (int j = 0; j < 4; ++j) {
        const float* xp = x + ((long)(wgb * 16 + m16) * T_LEN + (t0 + tl0 + j))
                              * I_DIM + quad * 8;
        af0[j] = pack8v(*(const floatx4*)xp,        *(const floatx4*)(xp + 4));
        af1[j] = pack8v(*(const floatx4*)(xp + 32), *(const floatx4*)(xp + 36));
    }

    #pragma unroll 1
    for (int wp = 0; wp < 8; ++wp) {
        #pragma unroll 1
        for (int gate = 0; gate < 3; ++gate) {
            const int u0 = wp * 32 + m16;
            float bs0, bs1, sc;
            if (gate < 2) {
                bs0 = b_ih[gate * 256 + u0]      + b_hh[gate * 256 + u0];
                bs1 = b_ih[gate * 256 + u0 + 16] + b_hh[gate * 256 + u0 + 16];
                sc  = L2E;
            } else {
                bs0 = b_ih[512 + u0];
                bs1 = b_ih[512 + u0 + 16];
                sc  = 2.0f * L2E;
            }
            const int gb = (wp * 6 + gate * 2) * 2;
            short8 b00 = *(const short8*)&wih_bf[((gb + 0) * 64 + lane) * 8];
            short8 b01 = *(const short8*)&wih_bf[((gb + 1) * 64 + lane) * 8];
            short8 b10 = *(const short8*)&wih_bf[((gb + 2) * 64 + lane) * 8];
            short8 b11 = *(const short8*)&wih_bf[((gb + 3) * 64 + lane) * 8];
            #pragma unroll
            for (int j = 0; j < 4; ++j) {
                floatx4 a0 = {0, 0, 0, 0}, a1 = {0, 0, 0, 0};
                a0 = __builtin_amdgcn_mfma_f32_16x16x32_bf16(af0[j], b00, a0, 0, 0, 0);
                a0 = __builtin_amdgcn_mfma_f32_16x16x32_bf16(af1[j], b01, a0, 0, 0, 0);
                a1 = __builtin_amdgcn_mfma_f32_16x16x32_bf16(af0[j], b10, a1, 0, 0, 0);
                a1 = __builtin_amdgcn_mfma_f32_16x16x32_bf16(af1[j], b11, a1, 0, 0, 0);
                short8 pk;
                pk[0] = (short)f2bf((a0[0] + bs0) * sc);
                pk[1] = (short)f2bf((a0[1] + bs0) * sc);
                pk[2] = (short)f2bf((a0[2] + bs0) * sc);
                pk[3] = (short)f2bf((a0[3] + bs0) * sc);
                pk[4] = (short)f2bf((a1[0] + bs1) * sc);
                pk[5] = (short)f2bf((a1[1] + bs1) * sc);
                pk[6] = (short)f2bf((a1[2] + bs1) * sc);
                pk[7] = (short)f2bf((a1[3] + bs1) * sc);
                long off = ((((long)(tl0 + j) * 32 + wgb) * 3 + gate) * 512
                            + wp * 64 + lane) * 8;
                *(short8*)&xg[off] = pk;
            }
        }
    }
}

// ---------------------------------------------------------------------------
// Scan: 8 waves (512 thr, 2 waves/SIMD), grid 32. All whh in registers,
// loaded as 48 coalesced 16B frags from pre-packed ws (no pack VALU).
// LDS = 16KB h dbuf. Raw lgkm-only barrier per step.
// Inner loop = R15's A/B-proven split-K with in-place rz sigmoids.
// ---------------------------------------------------------------------------
__global__ __launch_bounds__(512, 2) void gru_scan8(
    const unsigned short* __restrict__ xg,
    const unsigned short* __restrict__ whh_bf,
    const float* __restrict__ b_hh,
    const float* __restrict__ w_lin,
    const float* __restrict__ b_lin,
    float* __restrict__ h_state,        // [512][256] fp32 chunk carry
    float* __restrict__ out,            // [1024]
    int t0, int tlen, int last)
{
    __shared__ __align__(16) unsigned short hbf[1024 * 8];     // 16 KB dbuf

    const int tid  = threadIdx.x;
    const int wave = tid >> 6;
    const int lane = tid & 63;
    const int m16  = lane & 15;
    const int quad = lane >> 4;
    const int wg   = blockIdx.x;

    for (int b = tid; b < 1024; b += 512)
        *(short8*)&hbf[b * 8] = (short8)0;

    // ---- h carry-in: zeros at t0==0, else h_state ------------------------
    float h_old[8] = {0, 0, 0, 0, 0, 0, 0, 0};
    if (t0 > 0) {
        unsigned short* hbn = &hbf[(t0 & 1) * 512 * 8];
        #pragma unroll
        for (int i = 0; i < 2; ++i) {
            #pragma unroll
            for (int r = 0; r < 4; ++r) {
                float v = h_state[(long)(wg * NB + quad * 4 + r) * H_DIM
                                  + wave * 32 + i * 16 + m16];
                h_old[i * 4 + r] = v;
                hbn[(wave * 64 + (i * 2 + (m16 >> 3)) * 16 + quad * 4 + r) * 8
                    + (m16 & 7)] = f2bf(v);
            }
        }
    }

    // ---- whh weights: 48 coalesced 16B loads from pre-packed ws ----------
    short8 whh[3][2][8];
    {
        const unsigned short* wb = &whh_bf[((long)wave * 48 * 64 + lane) * 8];
        #pragma unroll
        for (int g = 0; g < 3; ++g)
            #pragma unroll
            for (int i = 0; i < 2; ++i)
                #pragma unroll
                for (int k = 0; k < 8; ++k)
                    whh[g][i][k] = *(const short8*)
                        &wb[(((g * 2 + i) * 8 + k) * 64) * 8];
    }
    float anb[2];   // 2*log2(e) * b_hh_n, folded into aN init
    anb[0] = 2.0f * L2E * b_hh[512 + wave * 32 + m16];
    anb[1] = 2.0f * L2E * b_hh[512 + wave * 32 + 16 + m16];

    // xg addressing (ushorts): slot = tid per plane; planes 4096 apart.
    const unsigned short* xgb = xg + (long)wg * 12288 + tid * 8;
    short8 pf0 = *(const short8*)&xgb[0];
    short8 pf1 = *(const short8*)&xgb[4096];
    short8 xnc = *(const short8*)&xgb[8192];
    const unsigned short* xgn = xgb + XG_TSTRIDE;   // -> step 1 (tlen >= 2)

    __syncthreads();

    #pragma unroll 1
    for (int tt = 0; tt < tlen; ++tt) {
        const int t = t0 + tt;
        // ---- acc init from prefetched xg (biases already folded) ---------
        floatx4 aR[2], aZ[2], aN[2];
        #pragma unroll
        for (int i = 0; i < 2; ++i) {
            #pragma unroll
            for (int r = 0; r < 4; ++r) {
                aR[i][r] = bf2f((unsigned short)pf0[i * 4 + r]);
                aZ[i][r] = bf2f((unsigned short)pf1[i * 4 + r]);
            }
            aN[i] = (floatx4){anb[i], anb[i], anb[i], anb[i]};
        }
        // ---- prefetch r,z planes of t+1 (full step of slack to use) ------
        pf0 = *(const short8*)&xgn[0];
        pf1 = *(const short8*)&xgn[4096];

        const unsigned short* hb = &hbf[(t & 1) * 512 * 8];

        // ---- K group 1: r,z chains (32 MFMAs) ----------------------------
        #pragma unroll
        for (int k = 0; k < 8; ++k) {
            short8 af = *(const short8*)&hb[(k * 64 + lane) * 8];
            aR[0] = __builtin_amdgcn_mfma_f32_16x16x32_bf16(af, whh[0][0][k], aR[0], 0, 0, 0);
            aR[1] = __builtin_amdgcn_mfma_f32_16x16x32_bf16(af, whh[0][1][k], aR[1], 0, 0, 0);
            aZ[0] = __builtin_amdgcn_mfma_f32_16x16x32_bf16(af, whh[1][0][k], aZ[0], 0, 0, 0);
            aZ[1] = __builtin_amdgcn_mfma_f32_16x16x32_bf16(af, whh[1][1][k], aZ[1], 0, 0, 0);
        }

        // ---- rz sigmoids IN-PLACE (no new registers); scheduler may
        //      interleave these trans ops under group 2's MFMAs ------------
        #pragma unroll
        for (int i = 0; i < 2; ++i) {
            #pragma unroll
            for (int r = 0; r < 4; ++r) {
                aR[i][r] = __builtin_amdgcn_rcpf(1.0f + __builtin_amdgcn_exp2f(-aR[i][r]));
                aZ[i][r] = __builtin_amdgcn_rcpf(1.0f + __builtin_amdgcn_exp2f(-aZ[i][r]));
            }
        }

        // ---- K group 2: n chains (16 MFMAs, af re-read) ------------------
        #pragma unroll
        for (int k = 0; k < 8; ++k) {
            short8 af = *(const short8*)&hb[(k * 64 + lane) * 8];
            aN[0] = __builtin_amdgcn_mfma_f32_16x16x32_bf16(af, whh[2][0][k], aN[0], 0, 0, 0);
            aN[1] = __builtin_amdgcn_mfma_f32_16x16x32_bf16(af, whh[2][1][k], aN[1], 0, 0, 0);
        }

        // ---- tail: av -> tanh -> blend; aR holds r, aZ holds z -----------
        unsigned short* hbn = &hbf[((t + 1) & 1) * 512 * 8];
        #pragma unroll
        for (int i = 0; i < 2; ++i) {
            float hv0, hv1, hv2, hv3;
            #pragma unroll
            for (int r = 0; r < 4; ++r) {
                const int e = i * 4 + r;
                float xnv = bf2f((unsigned short)xnc[i * 4 + r]);
                float av = xnv + aR[i][r] * aN[i][r];          // = 2*log2e*av
                float tn = 1.0f - 2.0f * __builtin_amdgcn_rcpf(1.0f + __builtin_amdgcn_exp2f(av));
                float hv = tn + aZ[i][r] * (h_old[e] - tn);    // (1-z)n + z*h
                h_old[e] = hv;
                if (r == 0) hv0 = hv; else if (r == 1) hv1 = hv;
                else if (r == 2) hv2 = hv; else hv3 = hv;
            }
            unsigned pk0, pk1;
            asm("v_cvt_pk_bf16_f32 %0, %1, %2" : "=v"(pk0) : "v"(hv0), "v"(hv1));
            asm("v_cvt_pk_bf16_f32 %0, %1, %2" : "=v"(pk1) : "v"(hv2), "v"(hv3));
            unsigned short* wb = &hbn[(wave * 64 + (i * 2 + (m16 >> 3)) * 16
                                       + quad * 4) * 8 + (m16 & 7)];
            wb[0]  = (unsigned short)(pk0 & 0xffffu);
            wb[8]  = (unsigned short)(pk0 >> 16);
            wb[16] = (unsigned short)(pk1 & 0xffffu);
            wb[24] = (unsigned short)(pk1 >> 16);
        }

        // ---- n-plane of t+1: loaded late (slack = barrier+MFMA ~1500cy) --
        xnc = *(const short8*)&xgn[8192];
        if (tt < tlen - 2) xgn += XG_TSTRIDE;

        // ---- RAW barrier: drain LDS only; xg loads stay in flight --------
        asm volatile("s_waitcnt lgkmcnt(0)" ::: "memory");
        __builtin_amdgcn_s_barrier();
    }

    // ---- h carry-out ------------------------------------------------------
    #pragma unroll
    for (int i = 0; i < 2; ++i)
        #pragma unroll
        for (int r = 0; r < 4; ++r)
            h_state[(long)(wg * NB + quad * 4 + r) * H_DIM
                    + wave * 32 + i * 16 + m16] = h_old[i * 4 + r];

    if (!last) return;

    // ---- epilogue: p = sigmoid(h_last . w_lin + b) -----------------------
    __syncthreads();
    float* hfin = (float*)hbf;
    #pragma unroll
    for (int i = 0; i < 2; ++i)
        #pragma unroll
        for (int r = 0; r < 4; ++r)
            hfin[(quad * 4 + r) * 256 + wave * 32 + i * 16 + m16] =
                h_old[i * 4 + r];
    __syncthreads();

    const int m = tid >> 5, j = tid & 31;
    float s = 0.0f;
    #pragma unroll
    for (int c = 0; c < 8; ++c)
        s += hfin[m * 256 + j + c * 32] * w_lin[j + c * 32];
    #pragma unroll
    for (int d = 16; d > 0; d >>= 1) s += __shfl_down(s, d, 32);
    if (j == 0) {
        float p = sigm(s + b_lin[0]);
        const int b = wg * NB + m;
        out[2 * b]     = p;
        out[2 * b + 1] = 1.0f - p;
    }
}

// ---------------------------------------------------------------------------
// Fallback: proven R7 kernel (1786 us) if workspace can't hold a 32-step chunk.
// ---------------------------------------------------------------------------
__global__ __launch_bounds__(512, 1) void gru_kernel(
    const float* __restrict__ x,
    const float* __restrict__ w_hh,
    const float* __restrict__ b_ih,
    const float* __restrict__ b_hh,
    const unsigned short* __restrict__ wih_ws,
    const float* __restrict__ w_lin,
    const float* __restrict__ b_lin,
    float* __restrict__ out)
{
    __shared__ __align__(16) unsigned short whn_lds[8192 * 8];
    __shared__ __align__(16) unsigned short hbf[1024 * 8];
    __shared__ __align__(16) unsigned short bias_lds[512 * 8];

    const int tid  = threadIdx.x;
    const int wave = tid >> 6;
    const int lane = tid & 63;
    const int m16  = lane & 15;
    const int quad = lane >> 4;
    const int wg   = blockIdx.x;

    for (int b = tid; b < 8192; b += 512) {
        const int l = b & 63;
        const int k = (b >> 6) & 7;
        const int g = (b >> 9) & 1;
        const int w = b >> 10;
        const int row = 512 + w * 32 + g * 16 + (l & 15);
        const int col = k * 32 + (l >> 4) * 8;
        const float* p = w_hh + row * H_DIM + col;
        *(short8*)&whn_lds[b * 8] = pack8v(*(const floatx4*)p,
                                           *(const floatx4*)(p + 4));
    }
    for (int b = tid; b < 1024; b += 512)
        *(short8*)&hbf[b * 8] = (short8)0;

    {
        const int u0 = wave * 32 + m16, u1 = u0 + 16;
        unsigned short* bl = &bias_lds[tid * 8];
        bl[0] = f2bf(b_ih[u0] + b_hh[u0]);
        bl[1] = f2bf(b_ih[u1] + b_hh[u1]);
        bl[2] = f2bf(b_ih[256 + u0] + b_hh[256 + u0]);
        bl[3] = f2bf(b_ih[256 + u1] + b_hh[256 + u1]);
        bl[4] = f2bf(b_hh[512 + u0]);
        bl[5] = f2bf(b_hh[512 + u1]);
        bl[6] = f2bf(b_ih[512 + u0]);
        bl[7] = f2bf(b_ih[512 + u1]);
    }

    short8 whh[4][8];
    #pragma unroll
    for (int g = 0; g < 4; ++g) {
        const int row = (g >> 1) * 256 + wave * 32 + (g & 1) * 16 + m16;
        const float* rp = w_hh + row * H_DIM;
        #pragma unroll
        for (int k = 0; k < 8; ++k) {
            const float* p = rp + k * 32 + quad * 8;
            whh[g][k] = pack8v(*(const floatx4*)p, *(const floatx4*)(p + 4));
        }
    }

    short8 wi[12];
    {
        const unsigned short* wib = &wih_ws[(wave * 6 * 2 * 64 + lane) * 8];
        #pragma unroll
        for (int j = 0; j < 12; ++j)
            wi[j] = *(const short8*)&wib[j * 64 * 8];
    }

    float h_old[8] = {0, 0, 0, 0, 0, 0, 0, 0};
    const float* xbase = x + (long)(wg * NB + m16) * T_LEN * I_DIM + quad * 8;

    __syncthreads();

    #pragma unroll 1
    for (int t = 0; t < T_LEN; ++t) {
        const float* xt = xbase + t * I_DIM;
        floatx4 x0 = *(const floatx4*)(xt);
        floatx4 x1 = *(const floatx4*)(xt + 4);
        floatx4 x2 = *(const floatx4*)(xt + 32);
        floatx4 x3 = *(const floatx4*)(xt + 36);

        floatx4 acc[4], an[2], xnl[2];
        #pragma unroll
        for (int g = 0; g < 4; ++g) acc[g] = (floatx4){0, 0, 0, 0};
        an[0] = an[1] = xnl[0] = xnl[1] = (floatx4){0, 0, 0, 0};

        const unsigned short* hb  = &hbf[(t & 1) * 512 * 8];
        const unsigned short* wnb = &whn_lds[(wave * 2 * 8 * 64 + lane) * 8];
        #pragma unroll
        for (int k = 0; k < 8; ++k) {
            short8 af  = *(const short8*)&hb[(k * 64 + lane) * 8];
            short8 wn0 = *(const short8*)&wnb[(k * 64) * 8];
            short8 wn1 = *(const short8*)&wnb[((8 + k) * 64) * 8];
            acc[0] = __builtin_amdgcn_mfma_f32_16x16x32_bf16(af, whh[0][k], acc[0], 0, 0, 0);
            acc[1] = __builtin_amdgcn_mfma_f32_16x16x32_bf16(af, whh[1][k], acc[1], 0, 0, 0);
            acc[2] = __builtin_amdgcn_mfma_f32_16x16x32_bf16(af, whh[2][k], acc[2], 0, 0, 0);
            acc[3] = __builtin_amdgcn_mfma_f32_16x16x32_bf16(af, whh[3][k], acc[3], 0, 0, 0);
            an[0]  = __builtin_amdgcn_mfma_f32_16x16x32_bf16(af, wn0, an[0], 0, 0, 0);
            an[1]  = __builtin_amdgcn_mfma_f32_16x16x32_bf16(af, wn1, an[1], 0, 0, 0);
        }

        short8 xa = pack8v(x0, x1);
        acc[0] = __builtin_amdgcn_mfma_f32_16x16x32_bf16(xa, wi[0],  acc[0], 0, 0, 0);
        acc[1] = __builtin_amdgcn_mfma_f32_16x16x32_bf16(xa, wi[2],  acc[1], 0, 0, 0);
        acc[2] = __builtin_amdgcn_mfma_f32_16x16x32_bf16(xa, wi[4],  acc[2], 0, 0, 0);
        acc[3] = __builtin_amdgcn_mfma_f32_16x16x32_bf16(xa, wi[6],  acc[3], 0, 0, 0);
        xnl[0] = __builtin_amdgcn_mfma_f32_16x16x32_bf16(xa, wi[8],  xnl[0], 0, 0, 0);
        xnl[1] = __builtin_amdgcn_mfma_f32_16x16x32_bf16(xa, wi[10], xnl[1], 0, 0, 0);
        xa = pack8v(x2, x3);
        acc[0] = __builtin_amdgcn_mfma_f32_16x16x32_bf16(xa, wi[1],  acc[0], 0, 0, 0);
        acc[1] = __builtin_amdgcn_mfma_f32_16x16x32_bf16(xa, wi[3],  acc[1], 0, 0, 0);
        acc[2] = __builtin_amdgcn_mfma_f32_16x16x32_bf16(xa, wi[5],  acc[2], 0, 0, 0);
        acc[3] = __builtin_amdgcn_mfma_f32_16x16x32_bf16(xa, wi[7],  acc[3], 0, 0, 0);
        xnl[0] = __builtin_amdgcn_mfma_f32_16x16x32_bf16(xa, wi[9],  xnl[0], 0, 0, 0);
        xnl[1] = __builtin_amdgcn_mfma_f32_16x16x32_bf16(xa, wi[11], xnl[1], 0, 0, 0);

        short8 bv = *(const short8*)&bias_lds[tid * 8];
        unsigned short* hbn = &hbf[((t + 1) & 1) * 512 * 8];
        #pragma unroll
        for (int i = 0; i < 2; ++i) {
            #pragma unroll
            for (int r = 0; r < 4; ++r) {
                const int idx = i * 4 + r;
                float rr = sigm(acc[i][r]     + bf2f((unsigned short)bv[i]));
                float zz = sigm(acc[2 + i][r] + bf2f((unsigned short)bv[2 + i]));
                float av = xnl[i][r] + bf2f((unsigned short)bv[6 + i])
                         + rr * (an[i][r] + bf2f((unsigned short)bv[4 + i]));
                float nn = 1.0f - 2.0f / (1.0f + __expf(2.0f * av));
                float hn = (1.0f - zz) * nn + zz * h_old[idx];
                h_old[idx] = hn;
                hbn[(wave * 64 + (i * 2 + (m16 >> 3)) * 16 + quad * 4 + r) * 8
                    + (m16 & 7)] = f2bf(hn);
            }
        }
        __syncthreads();
    }

    __syncthreads();
    float* hfin = (float*)hbf;
    #pragma unroll
    for (int i = 0; i < 2; ++i)
        #pragma unroll
        for (int r = 0; r < 4; ++r)
            hfin[(quad * 4 + r) * 256 + wave * 32 + i * 16 + m16] =
                h_old[i * 4 + r];
    __syncthreads();

    const int m = tid >> 5, j = tid & 31;
    float s = 0.0f;
    #pragma unroll
    for (int c = 0; c < 8; ++c)
        s += hfin[m * 256 + j + c * 32] * w_lin[j + c * 32];
    #pragma unroll
    for (int d = 16; d > 0; d >>= 1) s += __shfl_down(s, d, 32);
    if (j == 0) {
        float p = sigm(s + b_lin[0]);
        const int b = wg * NB + m;
        out[2 * b]     = p;
        out[2 * b + 1] = 1.0f - p;
    }
}

extern "C" void kernel_launch(void* const* d_in, const int* in_sizes, int n_in,
                              void* d_out, int out_size, void* d_ws, size_t ws_size,
                              hipStream_t stream) {
    const float* x     = (const float*)d_in[0];
    const float* w_ih0 = (const float*)d_in[1];
    const float* w_hh0 = (const float*)d_in[2];
    const float* b_ih0 = (const float*)d_in[3];
    const float* b_hh0 = (const float*)d_in[4];
    // d_in[5..8]: layer-1 params — dead code in the reference
    const float* w_lin = (const float*)d_in[9];
    const float* b_lin = (const float*)d_in[10];
    float* out = (float*)d_out;

    unsigned short* wih_bf = (unsigned short*)d_ws;
    cvt_wih_kernel<<<24, 256, 0, stream>>>(w_ih0, wih_bf);

    // largest chunk length whose xg buffer fits the workspace
    int Tc = 0;
    for (int c = 256; c >= 32; c >>= 1)
        if (ws_size >= XG_OFF + (size_t)c * XG_PER_T) { Tc = c; break; }

    if (Tc) {
        float* h_state = (float*)((char*)d_ws + HSTATE_OFF);
        unsigned short* whh_bf = (unsigned short*)((char*)d_ws + WHH_OFF);
        unsigned short* xg = (unsigned short*)((char*)d_ws + XG_OFF);
        cvt_whh_kernel<<<96, 256, 0, stream>>>(w_hh0, whh_bf);
        for (int t0 = 0; t0 < T_LEN; t0 += Tc) {
            xg_kernel<<<32 * (Tc / 16), 256, 0, stream>>>(x, wih_bf, xg,
                                                          b_ih0, b_hh0, t0);
            gru_scan8<<<NWG, 512, 0, stream>>>(xg, whh_bf, b_hh0,
                                               w_lin, b_lin, h_state, out,
                                               t0, Tc,
                                               (t0 + Tc >= T_LEN) ? 1 : 0);
        }
    } else {
        gru_kernel<<<NWG, 512, 0, stream>>>(x, w_hh0, b_ih0, b_hh0, wih_bf,
                                            w_lin, b_lin, out);
    }
}